// Round 8
// baseline (611.292 us; speedup 1.0000x reference)
//
#include <hip/hip_runtime.h>

#define T_TOK 4096
#define H_DIM 1024
#define I_DIM 4096
#define NE 8
#define INTER_ROWS 9216

typedef _Float16 f16;
typedef _Float16 f16x8 __attribute__((ext_vector_type(8)));
typedef _Float16 f16x4 __attribute__((ext_vector_type(4)));
typedef float f32x4 __attribute__((ext_vector_type(4)));

#define GLOBAL_AS __attribute__((address_space(1)))
#define LDS_AS __attribute__((address_space(3)))

__device__ __forceinline__ void gload_lds16(const void* g, void* l) {
  __builtin_amdgcn_global_load_lds((GLOBAL_AS const unsigned int*)g,
                                   (LDS_AS unsigned int*)l, 16, 0, 0);
}

#define VM0() asm volatile("s_waitcnt vmcnt(0)" ::: "memory")
#define BARF()                          \
  do {                                  \
    asm volatile("" ::: "memory");      \
    __builtin_amdgcn_s_barrier();       \
    asm volatile("" ::: "memory");      \
  } while (0)
#define PRIO1() __builtin_amdgcn_s_setprio(1)
#define PRIO0() __builtin_amdgcn_s_setprio(0)

// ---------------------------------------------------------------- cast x -> fp16
__global__ void cast_x_kernel(const float* __restrict__ x, f16* __restrict__ xh) {
  int i = blockIdx.x * 256 + threadIdx.x;
  float4 v = reinterpret_cast<const float4*>(x)[i];
  f16x4 o = {(f16)v.x, (f16)v.y, (f16)v.z, (f16)v.w};
  reinterpret_cast<f16x4*>(xh)[i] = o;
}

// ---------------------------------------------------------------- transpose+cast weights
// z<16: w1/w3 [H][I] -> interleaved w13t [8192][1024]:
//   w1 col c -> row (c>>5)*64 + (c&31);  w3 col c -> row (c>>5)*64 + 32 + (c&31)
// z>=16: w2 [I][H] -> w2t [H][I].  Writes widened to f16x8 (16 B/lane).
__global__ __launch_bounds__(256) void transpose_cast_kernel(
    const float* __restrict__ w1s, const float* __restrict__ w3s,
    const float* __restrict__ w2s, f16* __restrict__ w13t, f16* __restrict__ w2t) {
  __shared__ float tile[64][65];
  const int z = blockIdx.z;
  const int tr = threadIdx.x >> 4;
  const int tc = (threadIdx.x & 15) * 4;
  if (z < 16) {
    int e = z & 7;
    const float* in = (z < 8 ? w1s : w3s) + (size_t)e * H_DIM * I_DIM;
    f16* out = w13t + (size_t)e * (2 * H_DIM * I_DIM);
    const int roff = (z < 8) ? 0 : 32;
    const int c0 = blockIdx.x * 64, r0 = blockIdx.y * 64;
#pragma unroll
    for (int i = 0; i < 4; ++i) {
      int r = tr + i * 16;
      float4 v = *reinterpret_cast<const float4*>(&in[(size_t)(r0 + r) * I_DIM + c0 + tc]);
      tile[r][tc] = v.x; tile[r][tc + 1] = v.y; tile[r][tc + 2] = v.z; tile[r][tc + 3] = v.w;
    }
    __syncthreads();
#pragma unroll
    for (int it = 0; it < 2; ++it) {
      int idx = it * 256 + threadIdx.x;
      int oc = idx >> 3;
      int ch = (idx & 7) * 8;
      int cg = c0 + oc;
      int rowo = ((cg >> 5) << 6) + roff + (cg & 31);
      f16x8 h;
#pragma unroll
      for (int j = 0; j < 8; ++j) h[j] = (f16)tile[ch + j][oc];
      *reinterpret_cast<f16x8*>(&out[(size_t)rowo * H_DIM + r0 + ch]) = h;
    }
  } else {
    int e = z - 16;
    const float* in = w2s + (size_t)e * H_DIM * I_DIM;
    f16* out = w2t + (size_t)e * H_DIM * I_DIM;
    const int r0 = blockIdx.x * 64, c0 = blockIdx.y * 64;
#pragma unroll
    for (int i = 0; i < 4; ++i) {
      int r = tr + i * 16;
      float4 v = *reinterpret_cast<const float4*>(&in[(size_t)(r0 + r) * H_DIM + c0 + tc]);
      tile[r][tc] = v.x; tile[r][tc + 1] = v.y; tile[r][tc + 2] = v.z; tile[r][tc + 3] = v.w;
    }
    __syncthreads();
#pragma unroll
    for (int it = 0; it < 2; ++it) {
      int idx = it * 256 + threadIdx.x;
      int oc = idx >> 3;
      int ch = (idx & 7) * 8;
      f16x8 h;
#pragma unroll
      for (int j = 0; j < 8; ++j) h[j] = (f16)tile[ch + j][oc];
      *reinterpret_cast<f16x8*>(&out[(size_t)(c0 + oc) * I_DIM + r0 + ch]) = h;
    }
  }
}

// ---------------------------------------------------------------- router (1 wave / token)
__global__ void router_kernel(const float* __restrict__ x, const float* __restrict__ gw,
                              int* __restrict__ counts, int* __restrict__ lists,
                              float* __restrict__ wgts) {
  const int t = blockIdx.x;
  const int l = threadIdx.x;
  const float* xr = x + (size_t)t * H_DIM;
  float acc[NE];
#pragma unroll
  for (int e = 0; e < NE; ++e) acc[e] = 0.f;
  for (int k = l; k < H_DIM; k += 64) {
    float xv = xr[k];
#pragma unroll
    for (int e = 0; e < NE; ++e) acc[e] += xv * gw[k * NE + e];
  }
#pragma unroll
  for (int e = 0; e < NE; ++e) {
    float v = acc[e];
#pragma unroll
    for (int off = 32; off > 0; off >>= 1) v += __shfl_xor(v, off);
    acc[e] = v;
  }
  if (l == 0) {
    int i1 = 0;
#pragma unroll
    for (int e = 1; e < NE; ++e)
      if (acc[e] > acc[i1]) i1 = e;
    int i2 = (i1 == 0) ? 1 : 0;
#pragma unroll
    for (int e = 0; e < NE; ++e)
      if (e != i1 && acc[e] > acc[i2]) i2 = e;
    float wA = 1.f / (1.f + __expf(acc[i2] - acc[i1]));
    float wB = 1.f - wA;
    int p1 = atomicAdd(&counts[i1], 1);
    lists[i1 * T_TOK + p1] = t;
    wgts[i1 * T_TOK + p1] = wA;
    int p2 = atomicAdd(&counts[i2], 1);
    lists[i2 * T_TOK + p2] = t;
    wgts[i2 * T_TOK + p2] = wB;
  }
}

// ---------------------------------------------------------------- padded prefix offsets
__global__ void prefix_kernel(const int* __restrict__ counts, int* __restrict__ bases) {
  if (threadIdx.x == 0) {
    int s = 0;
#pragma unroll
    for (int e = 0; e < NE; ++e) {
      bases[e] = s;
      s += (counts[e] + 127) & ~127;
    }
  }
}

// common fragment-load / mfma macros (shared layout both GEMMs)
#define LDAm(DST, kh, SBASE)                                                      \
  {                                                                               \
    _Pragma("unroll") for (int m_ = 0; m_ < 8; ++m_) {                            \
      int row = wm * 128 + m_ * 16 + lrow;                                        \
      DST[m_] = *reinterpret_cast<const f16x8*>(                                  \
          &SBASE[row * 64 + (((kh)*4 + lk) ^ (row & 7)) * 8]);                    \
    }                                                                             \
  }
#define LDBm(DST, kh, np, SBBASE)                                                 \
  {                                                                               \
    _Pragma("unroll") for (int n_ = 0; n_ < 2; ++n_) {                            \
      int row = wn * 64 + ((np)*2 + n_) * 16 + lrow;                              \
      DST[n_] = *reinterpret_cast<const f16x8*>(                                  \
          &SBBASE[row * 64 + (((kh)*4 + lk) ^ (row & 7)) * 8]);                   \
    }                                                                             \
  }
#define MFm(AF, BF, np)                                                           \
  {                                                                               \
    PRIO1();                                                                      \
    _Pragma("unroll") for (int m_ = 0; m_ < 8; ++m_)                              \
        _Pragma("unroll") for (int n_ = 0; n_ < 2; ++n_)                          \
            acc[m_][(np)*2 + n_] = __builtin_amdgcn_mfma_f32_16x16x32_f16(        \
                AF[m_], BF[n_], acc[m_][(np)*2 + n_], 0, 0, 0);                   \
    PRIO0();                                                                      \
  }

// ================================================================ GEMM A
// inter = silu(x@w1)*(x@w3), w13t interleaved. Block 256 tok x 256 w13-rows,
// BK=64, dbuf-2 (128 KiB), 512 thr / 8 waves (2m x 4n), wave 128x64.
// XCD-affine decode: xcd = wgid&7 runs x in {xcd*4..+3} -> B-panels L2-resident.
// m201-order phases: reads/stage BEFORE barrier, MFMA on prev-phase frags after.
__global__ __launch_bounds__(512, 1) void gemm_a_kernel(
    const f16* __restrict__ xh, const f16* __restrict__ w13t,
    const int* __restrict__ counts, const int* __restrict__ bases,
    const int* __restrict__ lists, f16* __restrict__ inter) {
  const int w = blockIdx.x;           // 0..511
  const int xcd = w & 7, q = w >> 3;  // q 0..63
  const int bx = xcd * 4 + (q & 3);   // 0..31
  const int by = q >> 2;              // 0..15
  const int z = blockIdx.z;
  const int cnt = counts[z];
  const int r0 = by * 256;
  if (r0 >= cnt) return;
  const int base = bases[z], pad = (cnt + 127) & ~127;
  const int c0 = bx * 256;
  const int tid = threadIdx.x, lane = tid & 63, wid = tid >> 6;
  const int wm = wid >> 2, wn = wid & 3, lrow = lane & 15, lk = lane >> 4;

  __shared__ __align__(16) f16 lds[2][32768];  // [A 256x64 | B 256x64] x dbuf

  const int* lst = lists + z * T_TOK;
  const f16* w13 = w13t + (size_t)z * (2 * H_DIM * I_DIM);

  const f16* sp[4][2];
  f16* dp[4][2];
#pragma unroll
  for (int j = 0; j < 2; ++j) {
    int cg = (wid * 2 + j) * 64 + lane;
    int rih = cg >> 3;
    int loct = (cg & 7) ^ (rih & 7);
    int t0 = lst[r0 + rih], t1 = lst[r0 + 128 + rih];
    sp[0][j] = xh + (size_t)t0 * H_DIM + loct * 8;
    sp[2][j] = xh + (size_t)t1 * H_DIM + loct * 8;
    sp[1][j] = w13 + (size_t)(c0 + rih) * H_DIM + loct * 8;
    sp[3][j] = w13 + (size_t)(c0 + 128 + rih) * H_DIM + loct * 8;
    dp[0][j] = &lds[0][cg * 8];
    dp[2][j] = &lds[0][8192 + cg * 8];
    dp[1][j] = &lds[0][16384 + cg * 8];
    dp[3][j] = &lds[0][24576 + cg * 8];
  }

#define STG(u, S, K)                                        \
  do {                                                      \
    gload_lds16(sp[u][0] + (K), dp[u][0] + (S)*32768);      \
    gload_lds16(sp[u][1] + (K), dp[u][1] + (S)*32768);      \
  } while (0)

  const f32x4 z4 = {0.f, 0.f, 0.f, 0.f};
  f32x4 acc[8][4];
#pragma unroll
  for (int m = 0; m < 8; ++m)
#pragma unroll
    for (int n = 0; n < 4; ++n) acc[m][n] = z4;

  f16x8 afA[8], afB[8], bfX[2], bfY[2];
  const int NT = H_DIM / 64;  // 16

  STG(0, 0, 0); STG(1, 0, 0); STG(2, 0, 0); STG(3, 0, 0);
  VM0(); BARF();
  { const f16* SA = lds[0]; const f16* SB = SA + 16384;
    LDAm(afA, 0, SA); LDBm(bfX, 0, 0, SB); }

  for (int t = 0; t < NT; ++t) {
    const f16* SA = lds[t & 1];
    const f16* SB = SA + 16384;
    const int S = (t + 1) & 1;
    const f16* SA2 = lds[S];
    const f16* SB2 = SA2 + 16384;
    const bool more = (t + 1 < NT);
    const int ks = (t + 1) * 64;
    // ph0
    if (more) { STG(0, S, ks); STG(1, S, ks); }
    LDBm(bfY, 0, 1, SB);
    BARF();
    MFm(afA, bfX, 0);
    // ph1
    if (more) { STG(2, S, ks); STG(3, S, ks); }
    LDAm(afB, 1, SA);
    LDBm(bfX, 1, 0, SB);
    BARF();
    MFm(afA, bfY, 1);
    // ph2
    LDBm(bfY, 1, 1, SB);
    BARF();
    MFm(afB, bfX, 0);
    // ph3: publish staged slot, prefetch next tile's first frags alongside MFMA
    VM0();
    BARF();
    if (more) { LDAm(afA, 0, SA2); LDBm(bfX, 0, 0, SB2); }
    MFm(afB, bfY, 1);
  }
#undef STG

  // epilogue: SwiGLU in-register (frags n / n+2 = w1 / w3 of the same orig cols)
#pragma unroll
  for (int m = 0; m < 8; ++m)
#pragma unroll
    for (int r = 0; r < 4; ++r) {
      int rowl = wm * 128 + m * 16 + lk * 4 + r;
      if (r0 + rowl < pad) {
        size_t grow = base + r0 + rowl;
#pragma unroll
        for (int n = 0; n < 2; ++n) {
          int col = (c0 >> 1) + wn * 32 + n * 16 + lrow;
          float v1 = acc[m][n][r];
          float v3 = acc[m][n + 2][r];
          float sv = v1 / (1.f + __expf(-v1));
          inter[grow * I_DIM + col] = (f16)(sv * v3);
        }
      }
    }
}

// ================================================================ GEMM B
// out[tok] += wgt * inter@w2t. Block 256 rows x 256 cols, split-K x2 (K=2048),
// BK=64, dbuf-2, 512 thr / 8 waves, wave 128x64. Same pipeline; XCD-affine:
// each XCD owns one B-panel (x = xcd>>1), 2 MB L2-resident.
__global__ __launch_bounds__(512, 1) void gemm_b_kernel(
    const f16* __restrict__ inter, const f16* __restrict__ w2t,
    const int* __restrict__ counts, const int* __restrict__ bases,
    const int* __restrict__ lists, const float* __restrict__ wgts,
    float* __restrict__ out) {
  const int w = blockIdx.x;           // 0..127
  const int xcd = w & 7, q = w >> 3;  // q 0..15
  const int bx = xcd >> 1;            // 0..3
  const int yid = (xcd & 1) * 16 + q; // 0..31
  const int rb = yid >> 1, kb = yid & 1;
  const int z = blockIdx.z;
  const int cnt = counts[z];
  const int r0 = rb * 256;
  if (r0 >= cnt) return;
  const int base = bases[z];
  const int c0 = bx * 256;
  const int tid = threadIdx.x, lane = tid & 63, wid = tid >> 6;
  const int wm = wid >> 2, wn = wid & 3, lrow = lane & 15, lk = lane >> 4;

  __shared__ __align__(16) f16 lds[2][32768];

  const int* lst = lists + z * T_TOK;
  const float* wgt = wgts + z * T_TOK;
  const f16* w2 = w2t + (size_t)z * I_DIM * H_DIM;
  const int K0 = kb * 2048;

  const f16* sp[4][2];
  f16* dp[4][2];
#pragma unroll
  for (int j = 0; j < 2; ++j) {
    int cg = (wid * 2 + j) * 64 + lane;
    int rih = cg >> 3;
    int loct = (cg & 7) ^ (rih & 7);
    // ragged-tail A rows land in allocated ws (w13t follows inter); discarded in epilogue
    sp[0][j] = inter + (size_t)(base + r0 + rih) * I_DIM + K0 + loct * 8;
    sp[2][j] = inter + (size_t)(base + r0 + 128 + rih) * I_DIM + K0 + loct * 8;
    sp[1][j] = w2 + (size_t)(c0 + rih) * I_DIM + K0 + loct * 8;
    sp[3][j] = w2 + (size_t)(c0 + 128 + rih) * I_DIM + K0 + loct * 8;
    dp[0][j] = &lds[0][cg * 8];
    dp[2][j] = &lds[0][8192 + cg * 8];
    dp[1][j] = &lds[0][16384 + cg * 8];
    dp[3][j] = &lds[0][24576 + cg * 8];
  }

#define STG(u, S, K)                                        \
  do {                                                      \
    gload_lds16(sp[u][0] + (K), dp[u][0] + (S)*32768);      \
    gload_lds16(sp[u][1] + (K), dp[u][1] + (S)*32768);      \
  } while (0)

  const f32x4 z4 = {0.f, 0.f, 0.f, 0.f};
  f32x4 acc[8][4];
#pragma unroll
  for (int m = 0; m < 8; ++m)
#pragma unroll
    for (int n = 0; n < 4; ++n) acc[m][n] = z4;

  f16x8 afA[8], afB[8], bfX[2], bfY[2];
  const int NT = 2048 / 64;  // 32

  STG(0, 0, 0); STG(1, 0, 0); STG(2, 0, 0); STG(3, 0, 0);
  VM0(); BARF();
  { const f16* SA = lds[0]; const f16* SB = SA + 16384;
    LDAm(afA, 0, SA); LDBm(bfX, 0, 0, SB); }

  for (int t = 0; t < NT; ++t) {
    const f16* SA = lds[t & 1];
    const f16* SB = SA + 16384;
    const int S = (t + 1) & 1;
    const f16* SA2 = lds[S];
    const f16* SB2 = SA2 + 16384;
    const bool more = (t + 1 < NT);
    const int ks = (t + 1) * 64;
    if (more) { STG(0, S, ks); STG(1, S, ks); }
    LDBm(bfY, 0, 1, SB);
    BARF();
    MFm(afA, bfX, 0);
    if (more) { STG(2, S, ks); STG(3, S, ks); }
    LDAm(afB, 1, SA);
    LDBm(bfX, 1, 0, SB);
    BARF();
    MFm(afA, bfY, 1);
    LDBm(bfY, 1, 1, SB);
    BARF();
    MFm(afB, bfX, 0);
    VM0();
    BARF();
    if (more) { LDAm(afA, 0, SA2); LDBm(bfX, 0, 0, SB2); }
    MFm(afB, bfY, 1);
  }
#undef STG

  // epilogue: ATOMIC accumulate (token in 2 experts' lists + split-K x2;
  // commutative fp32 adds on a zeroed buffer = deterministic)
#pragma unroll
  for (int m = 0; m < 8; ++m)
#pragma unroll
    for (int r = 0; r < 4; ++r) {
      int ri = r0 + wm * 128 + m * 16 + lk * 4 + r;
      if (ri < cnt) {
        int tok = lst[ri];
        float wg = wgt[ri];
        float* orow = out + (size_t)tok * H_DIM + c0 + wn * 64 + lrow;
#pragma unroll
        for (int n = 0; n < 4; ++n) atomicAdd(&orow[n * 16], wg * acc[m][n][r]);
      }
    }
}

// ---------------------------------------------------------------- host
extern "C" void kernel_launch(void* const* d_in, const int* in_sizes, int n_in,
                              void* d_out, int out_size, void* d_ws, size_t ws_size,
                              hipStream_t stream) {
  const float* x = (const float*)d_in[0];
  const float* gw = (const float*)d_in[1];
  const float* w1s = (const float*)d_in[2];
  const float* w2s = (const float*)d_in[3];
  const float* w3s = (const float*)d_in[4];
  float* out = (float*)d_out;

  char* ws = (char*)d_ws;
  f16* xh = (f16*)ws;                                   // 8 MiB
  f16* inter = (f16*)(ws + ((size_t)8 << 20));          // 72 MiB (9216 rows)
  f16* w13t = (f16*)(ws + ((size_t)80 << 20));          // 128 MiB (interleaved w1|w3)
  f16* w2t = (f16*)(ws + ((size_t)208 << 20));          // 64 MiB
  char* meta = ws + ((size_t)272 << 20);
  int* counts = (int*)meta;
  int* bases = (int*)(meta + 512);
  int* lists = (int*)(meta + 1024);
  float* wgts = (float*)(meta + 1024 + (size_t)NE * T_TOK * 4);

  hipMemsetAsync(out, 0, (size_t)out_size * sizeof(float), stream);
  hipMemsetAsync(meta, 0, 1024 + (size_t)NE * T_TOK * 8, stream);

  cast_x_kernel<<<dim3((T_TOK * H_DIM) / (4 * 256)), dim3(256), 0, stream>>>(x, xh);
  router_kernel<<<dim3(T_TOK), dim3(64), 0, stream>>>(x, gw, counts, lists, wgts);
  prefix_kernel<<<dim3(1), dim3(64), 0, stream>>>(counts, bases);
  transpose_cast_kernel<<<dim3(64, 16, 24), dim3(256), 0, stream>>>(
      w1s, w3s, w2s, w13t, w2t);
  gemm_a_kernel<<<dim3(512, 1, NE), dim3(512), 0, stream>>>(
      xh, w13t, counts, bases, lists, inter);
  gemm_b_kernel<<<dim3(128, 1, NE), dim3(512), 0, stream>>>(
      inter, w2t, counts, bases, lists, wgts, out);
}

// Round 9
// 552.791 us; speedup vs baseline: 1.1058x; 1.1058x over previous
//
#include <hip/hip_runtime.h>

#define T_TOK 4096
#define H_DIM 1024
#define I_DIM 4096
#define NE 8
#define INTER_ROWS 9216

typedef _Float16 f16;
typedef _Float16 f16x8 __attribute__((ext_vector_type(8)));
typedef _Float16 f16x4 __attribute__((ext_vector_type(4)));
typedef float f32x4 __attribute__((ext_vector_type(4)));

#define GLOBAL_AS __attribute__((address_space(1)))
#define LDS_AS __attribute__((address_space(3)))

__device__ __forceinline__ void gload_lds16(const void* g, void* l) {
  __builtin_amdgcn_global_load_lds((GLOBAL_AS const unsigned int*)g,
                                   (LDS_AS unsigned int*)l, 16, 0, 0);
}

#define VM0() asm volatile("s_waitcnt vmcnt(0)" ::: "memory")
#define BARF()                          \
  do {                                  \
    asm volatile("" ::: "memory");      \
    __builtin_amdgcn_s_barrier();       \
    asm volatile("" ::: "memory");      \
  } while (0)
#define PRIO1() __builtin_amdgcn_s_setprio(1)
#define PRIO0() __builtin_amdgcn_s_setprio(0)

// ---------------------------------------------------------------- cast x -> fp16
__global__ void cast_x_kernel(const float* __restrict__ x, f16* __restrict__ xh) {
  int i = blockIdx.x * 256 + threadIdx.x;
  float4 v = reinterpret_cast<const float4*>(x)[i];
  f16x4 o = {(f16)v.x, (f16)v.y, (f16)v.z, (f16)v.w};
  reinterpret_cast<f16x4*>(xh)[i] = o;
}

// ---------------------------------------------------------------- transpose+cast weights
// z<16: w1/w3 [H][I] -> interleaved w13t [8192][1024]:
//   w1 col c -> row (c>>5)*64 + (c&31);  w3 col c -> row (c>>5)*64 + 32 + (c&31)
// z>=16: w2 [I][H] -> w2t [H][I]
__global__ __launch_bounds__(256) void transpose_cast_kernel(
    const float* __restrict__ w1s, const float* __restrict__ w3s,
    const float* __restrict__ w2s, f16* __restrict__ w13t, f16* __restrict__ w2t) {
  __shared__ float tile[64][65];
  const int z = blockIdx.z;
  const int tr = threadIdx.x >> 4;
  const int tc = (threadIdx.x & 15) * 4;
  if (z < 16) {
    int e = z & 7;
    const float* in = (z < 8 ? w1s : w3s) + (size_t)e * H_DIM * I_DIM;
    f16* out = w13t + (size_t)e * (2 * H_DIM * I_DIM);
    const int roff = (z < 8) ? 0 : 32;
    const int c0 = blockIdx.x * 64, r0 = blockIdx.y * 64;
#pragma unroll
    for (int i = 0; i < 4; ++i) {
      int r = tr + i * 16;
      float4 v = *reinterpret_cast<const float4*>(&in[(size_t)(r0 + r) * I_DIM + c0 + tc]);
      tile[r][tc] = v.x; tile[r][tc + 1] = v.y; tile[r][tc + 2] = v.z; tile[r][tc + 3] = v.w;
    }
    __syncthreads();
#pragma unroll
    for (int i = 0; i < 4; ++i) {
      int oc = tr + i * 16;
      int cg = c0 + oc;
      int rowo = ((cg >> 5) << 6) + roff + (cg & 31);
      f16x4 h;
#pragma unroll
      for (int j = 0; j < 4; ++j) h[j] = (f16)tile[tc + j][oc];
      *reinterpret_cast<f16x4*>(&out[(size_t)rowo * H_DIM + r0 + tc]) = h;
    }
  } else {
    int e = z - 16;
    const float* in = w2s + (size_t)e * H_DIM * I_DIM;
    f16* out = w2t + (size_t)e * H_DIM * I_DIM;
    const int r0 = blockIdx.x * 64, c0 = blockIdx.y * 64;
#pragma unroll
    for (int i = 0; i < 4; ++i) {
      int r = tr + i * 16;
      float4 v = *reinterpret_cast<const float4*>(&in[(size_t)(r0 + r) * H_DIM + c0 + tc]);
      tile[r][tc] = v.x; tile[r][tc + 1] = v.y; tile[r][tc + 2] = v.z; tile[r][tc + 3] = v.w;
    }
    __syncthreads();
#pragma unroll
    for (int i = 0; i < 4; ++i) {
      int oc = tr + i * 16;
      f16x4 h;
#pragma unroll
      for (int j = 0; j < 4; ++j) h[j] = (f16)tile[tc + j][oc];
      *reinterpret_cast<f16x4*>(&out[(size_t)(c0 + oc) * I_DIM + r0 + tc]) = h;
    }
  }
}

// ---------------------------------------------------------------- router (1 wave / token)
__global__ void router_kernel(const float* __restrict__ x, const float* __restrict__ gw,
                              int* __restrict__ counts, int* __restrict__ lists,
                              float* __restrict__ wgts) {
  const int t = blockIdx.x;
  const int l = threadIdx.x;
  const float* xr = x + (size_t)t * H_DIM;
  float acc[NE];
#pragma unroll
  for (int e = 0; e < NE; ++e) acc[e] = 0.f;
  for (int k = l; k < H_DIM; k += 64) {
    float xv = xr[k];
#pragma unroll
    for (int e = 0; e < NE; ++e) acc[e] += xv * gw[k * NE + e];
  }
#pragma unroll
  for (int e = 0; e < NE; ++e) {
    float v = acc[e];
#pragma unroll
    for (int off = 32; off > 0; off >>= 1) v += __shfl_xor(v, off);
    acc[e] = v;
  }
  if (l == 0) {
    int i1 = 0;
#pragma unroll
    for (int e = 1; e < NE; ++e)
      if (acc[e] > acc[i1]) i1 = e;
    int i2 = (i1 == 0) ? 1 : 0;
#pragma unroll
    for (int e = 0; e < NE; ++e)
      if (e != i1 && acc[e] > acc[i2]) i2 = e;
    float wA = 1.f / (1.f + __expf(acc[i2] - acc[i1]));
    float wB = 1.f - wA;
    int p1 = atomicAdd(&counts[i1], 1);
    lists[i1 * T_TOK + p1] = t;
    wgts[i1 * T_TOK + p1] = wA;
    int p2 = atomicAdd(&counts[i2], 1);
    lists[i2 * T_TOK + p2] = t;
    wgts[i2 * T_TOK + p2] = wB;
  }
}

// ---------------------------------------------------------------- padded prefix offsets
__global__ void prefix_kernel(const int* __restrict__ counts, int* __restrict__ bases) {
  if (threadIdx.x == 0) {
    int s = 0;
#pragma unroll
    for (int e = 0; e < NE; ++e) {
      bases[e] = s;
      s += (counts[e] + 127) & ~127;
    }
  }
}

// common fragment-load / mfma macros (gemm_a geometry: 8 waves 2m x 4n, wave 128x64)
#define LDAm(DST, kh, SBASE)                                                      \
  {                                                                               \
    _Pragma("unroll") for (int m_ = 0; m_ < 8; ++m_) {                            \
      int row = wm * 128 + m_ * 16 + lrow;                                        \
      DST[m_] = *reinterpret_cast<const f16x8*>(                                  \
          &SBASE[row * 64 + (((kh)*4 + lk) ^ (row & 7)) * 8]);                    \
    }                                                                             \
  }
#define LDBm(DST, kh, np, SBBASE)                                                 \
  {                                                                               \
    _Pragma("unroll") for (int n_ = 0; n_ < 2; ++n_) {                            \
      int row = wn * 64 + ((np)*2 + n_) * 16 + lrow;                              \
      DST[n_] = *reinterpret_cast<const f16x8*>(                                  \
          &SBBASE[row * 64 + (((kh)*4 + lk) ^ (row & 7)) * 8]);                   \
    }                                                                             \
  }
#define MFm(AF, BF, np)                                                           \
  {                                                                               \
    PRIO1();                                                                      \
    _Pragma("unroll") for (int m_ = 0; m_ < 8; ++m_)                              \
        _Pragma("unroll") for (int n_ = 0; n_ < 2; ++n_)                          \
            acc[m_][(np)*2 + n_] = __builtin_amdgcn_mfma_f32_16x16x32_f16(        \
                AF[m_], BF[n_], acc[m_][(np)*2 + n_], 0, 0, 0);                   \
    PRIO0();                                                                      \
  }

// ================================================================ GEMM A (r7 verbatim)
// inter = silu(x@w1)*(x@w3), w13t interleaved. Block 256 tok x 256 w13-rows,
// BK=64, dbuf-2 (128 KiB), 512 thr / 8 waves (2m x 4n), wave 128x64.
__global__ __launch_bounds__(512, 1) void gemm_a_kernel(
    const f16* __restrict__ xh, const f16* __restrict__ w13t,
    const int* __restrict__ counts, const int* __restrict__ bases,
    const int* __restrict__ lists, f16* __restrict__ inter) {
  const int z = blockIdx.z;
  const int cnt = counts[z];
  const int r0 = blockIdx.y * 256;
  if (r0 >= cnt) return;
  const int base = bases[z], pad = (cnt + 127) & ~127;
  const int c0 = blockIdx.x * 256;
  const int tid = threadIdx.x, lane = tid & 63, wid = tid >> 6;
  const int wm = wid >> 2, wn = wid & 3, lrow = lane & 15, lk = lane >> 4;

  __shared__ __align__(16) f16 lds[2][32768];

  const int* lst = lists + z * T_TOK;
  const f16* w13 = w13t + (size_t)z * (2 * H_DIM * I_DIM);

  const f16* sp[4][2];
  f16* dp[4][2];
#pragma unroll
  for (int j = 0; j < 2; ++j) {
    int cg = (wid * 2 + j) * 64 + lane;
    int rih = cg >> 3;
    int loct = (cg & 7) ^ (rih & 7);
    int t0 = lst[r0 + rih], t1 = lst[r0 + 128 + rih];
    sp[0][j] = xh + (size_t)t0 * H_DIM + loct * 8;
    sp[2][j] = xh + (size_t)t1 * H_DIM + loct * 8;
    sp[1][j] = w13 + (size_t)(c0 + rih) * H_DIM + loct * 8;
    sp[3][j] = w13 + (size_t)(c0 + 128 + rih) * H_DIM + loct * 8;
    dp[0][j] = &lds[0][cg * 8];
    dp[2][j] = &lds[0][8192 + cg * 8];
    dp[1][j] = &lds[0][16384 + cg * 8];
    dp[3][j] = &lds[0][24576 + cg * 8];
  }

#define STG(u, S, K)                                        \
  do {                                                      \
    gload_lds16(sp[u][0] + (K), dp[u][0] + (S)*32768);      \
    gload_lds16(sp[u][1] + (K), dp[u][1] + (S)*32768);      \
  } while (0)

  const f32x4 z4 = {0.f, 0.f, 0.f, 0.f};
  f32x4 acc[8][4];
#pragma unroll
  for (int m = 0; m < 8; ++m)
#pragma unroll
    for (int n = 0; n < 4; ++n) acc[m][n] = z4;

  f16x8 afA[8], afB[8], bfX[2], bfY[2];
  const int NT = H_DIM / 64;  // 16

  STG(0, 0, 0); STG(1, 0, 0); STG(2, 0, 0); STG(3, 0, 0);
  VM0(); BARF();
  { const f16* SA = lds[0]; const f16* SB = SA + 16384;
    LDAm(afA, 0, SA); LDBm(bfX, 0, 0, SB); }

  for (int t = 0; t < NT; ++t) {
    const f16* SA = lds[t & 1];
    const f16* SB = SA + 16384;
    const int S = (t + 1) & 1;
    const f16* SA2 = lds[S];
    const f16* SB2 = SA2 + 16384;
    const bool more = (t + 1 < NT);
    const int ks = (t + 1) * 64;
    if (more) { STG(0, S, ks); STG(1, S, ks); }
    LDBm(bfY, 0, 1, SB);
    BARF();
    MFm(afA, bfX, 0);
    if (more) { STG(2, S, ks); STG(3, S, ks); }
    LDAm(afB, 1, SA);
    LDBm(bfX, 1, 0, SB);
    BARF();
    MFm(afA, bfY, 1);
    LDBm(bfY, 1, 1, SB);
    BARF();
    MFm(afB, bfX, 0);
    VM0();
    BARF();
    if (more) { LDAm(afA, 0, SA2); LDBm(bfX, 0, 0, SB2); }
    MFm(afB, bfY, 1);
  }
#undef STG

#pragma unroll
  for (int m = 0; m < 8; ++m)
#pragma unroll
    for (int r = 0; r < 4; ++r) {
      int rowl = wm * 128 + m * 16 + lk * 4 + r;
      if (r0 + rowl < pad) {
        size_t grow = base + r0 + rowl;
#pragma unroll
        for (int n = 0; n < 2; ++n) {
          int col = (c0 >> 1) + wn * 32 + n * 16 + lrow;
          float v1 = acc[m][n][r];
          float v3 = acc[m][n + 2][r];
          float sv = v1 / (1.f + __expf(-v1));
          inter[grow * I_DIM + col] = (f16)(sv * v3);
        }
      }
    }
}

// ================================================================ GEMM B (rebuilt for balance)
// out[tok] += wgt * inter@w2t. Tile 128 rows x 128 cols, split-K x2 (K=2048 each),
// BK=64, dbuf-2 (64 KiB -> 2 blocks/CU), 256 thr / 4 waves (2m x 2n), wave 64x64.
// ~1100 active blocks (vs r8's ~280) -> tail amortized. Same proven 4-phase skeleton.
__global__ __launch_bounds__(256, 2) void gemm_b_kernel(
    const f16* __restrict__ inter, const f16* __restrict__ w2t,
    const int* __restrict__ counts, const int* __restrict__ bases,
    const int* __restrict__ lists, const float* __restrict__ wgts,
    float* __restrict__ out) {
  const int z = blockIdx.z;
  const int cnt = counts[z];
  const int rb = blockIdx.y >> 1, kb = blockIdx.y & 1;
  const int r0 = rb * 128;
  if (r0 >= cnt) return;
  const int base = bases[z];
  const int c0 = blockIdx.x * 128;
  const int tid = threadIdx.x, lane = tid & 63, wid = tid >> 6;  // wid 0..3
  const int wm = wid >> 1, wn = wid & 1, lrow = lane & 15, lk = lane >> 4;

  __shared__ __align__(16) f16 lds[2][16384];  // [A 128x64 | B 128x64] = 32 KiB/slot

  const int* lst = lists + z * T_TOK;
  const float* wgt = wgts + z * T_TOK;
  const f16* w2 = w2t + (size_t)z * I_DIM * H_DIM;
  const int K0 = kb * 2048;

  // staging: 4 A-units + 4 B-units of 256 chunks (16B) each; linear LDS dest,
  // source inverse-swizzled (loct = oct ^ (row&7)). Pad rows (cnt..pad) of inter
  // are written by gemm_a (finite garbage) and discarded in the epilogue.
  const f16 *spA[4], *spB[4];
  f16 *dpA[4], *dpB[4];
#pragma unroll
  for (int u = 0; u < 4; ++u) {
    int cg = u * 256 + tid;          // 0..1023
    int row = cg >> 3;               // 0..127
    int loct = (cg & 7) ^ (row & 7);
    spA[u] = inter + (size_t)(base + r0 + row) * I_DIM + K0 + loct * 8;
    spB[u] = w2 + (size_t)(c0 + row) * I_DIM + K0 + loct * 8;
    dpA[u] = &lds[0][cg * 8];
    dpB[u] = &lds[0][8192 + cg * 8];
  }

#define STGA4(S, K)                                                   \
  do {                                                                \
    _Pragma("unroll") for (int u_ = 0; u_ < 4; ++u_)                  \
        gload_lds16(spA[u_] + (K), dpA[u_] + (S)*16384);              \
  } while (0)
#define STGB4(S, K)                                                   \
  do {                                                                \
    _Pragma("unroll") for (int u_ = 0; u_ < 4; ++u_)                  \
        gload_lds16(spB[u_] + (K), dpB[u_] + (S)*16384);              \
  } while (0)

#define LDA2(DST, kh, SBASE)                                                      \
  {                                                                               \
    _Pragma("unroll") for (int m_ = 0; m_ < 4; ++m_) {                            \
      int row = wm * 64 + m_ * 16 + lrow;                                         \
      DST[m_] = *reinterpret_cast<const f16x8*>(                                  \
          &SBASE[row * 64 + (((kh)*4 + lk) ^ (row & 7)) * 8]);                    \
    }                                                                             \
  }
#define LDB2(DST, kh, np, SBBASE)                                                 \
  {                                                                               \
    _Pragma("unroll") for (int n_ = 0; n_ < 2; ++n_) {                            \
      int row = wn * 64 + ((np)*2 + n_) * 16 + lrow;                              \
      DST[n_] = *reinterpret_cast<const f16x8*>(                                  \
          &SBBASE[row * 64 + (((kh)*4 + lk) ^ (row & 7)) * 8]);                   \
    }                                                                             \
  }
#define MF2(AF, BF, np)                                                           \
  {                                                                               \
    PRIO1();                                                                      \
    _Pragma("unroll") for (int m_ = 0; m_ < 4; ++m_)                              \
        _Pragma("unroll") for (int n_ = 0; n_ < 2; ++n_)                          \
            acc[m_][(np)*2 + n_] = __builtin_amdgcn_mfma_f32_16x16x32_f16(        \
                AF[m_], BF[n_], acc[m_][(np)*2 + n_], 0, 0, 0);                   \
    PRIO0();                                                                      \
  }

  const f32x4 z4 = {0.f, 0.f, 0.f, 0.f};
  f32x4 acc[4][4];
#pragma unroll
  for (int m = 0; m < 4; ++m)
#pragma unroll
    for (int n = 0; n < 4; ++n) acc[m][n] = z4;

  f16x8 afA[4], afB[4], bfX[2], bfY[2];
  const int NT = 2048 / 64;  // 32

  STGA4(0, 0); STGB4(0, 0);
  VM0(); BARF();
  { const f16* SA = lds[0]; const f16* SB = SA + 8192;
    LDA2(afA, 0, SA); LDB2(bfX, 0, 0, SB); }

  for (int t = 0; t < NT; ++t) {
    const f16* SA = lds[t & 1];
    const f16* SB = SA + 8192;
    const int S = (t + 1) & 1;
    const f16* SA2 = lds[S];
    const f16* SB2 = SA2 + 8192;
    const bool more = (t + 1 < NT);
    const int ks = (t + 1) * 64;
    // ph0: stage A of next tile
    if (more) STGA4(S, ks);
    LDB2(bfY, 0, 1, SB);
    BARF();
    MF2(afA, bfX, 0);
    // ph1: stage B of next tile
    if (more) STGB4(S, ks);
    LDA2(afB, 1, SA);
    LDB2(bfX, 1, 0, SB);
    BARF();
    MF2(afA, bfY, 1);
    // ph2
    LDB2(bfY, 1, 1, SB);
    BARF();
    MF2(afB, bfX, 0);
    // ph3: confirm staged slot (issued 2 phases ago), publish, prefetch next frags
    VM0();
    BARF();
    if (more) { LDA2(afA, 0, SA2); LDB2(bfX, 0, 0, SB2); }
    MF2(afB, bfY, 1);
  }
#undef STGA4
#undef STGB4

  // epilogue: ATOMIC accumulate (token in 2 experts' lists + split-K x2;
  // fp32 adds on a zeroed buffer)
#pragma unroll
  for (int m = 0; m < 4; ++m)
#pragma unroll
    for (int r = 0; r < 4; ++r) {
      int ri = r0 + wm * 64 + m * 16 + lk * 4 + r;
      if (ri < cnt) {
        int tok = lst[ri];
        float wg = wgt[ri];
        float* orow = out + (size_t)tok * H_DIM + c0 + wn * 64 + lrow;
#pragma unroll
        for (int n = 0; n < 4; ++n) atomicAdd(&orow[n * 16], wg * acc[m][n][r]);
      }
    }
}

// ---------------------------------------------------------------- host
extern "C" void kernel_launch(void* const* d_in, const int* in_sizes, int n_in,
                              void* d_out, int out_size, void* d_ws, size_t ws_size,
                              hipStream_t stream) {
  const float* x = (const float*)d_in[0];
  const float* gw = (const float*)d_in[1];
  const float* w1s = (const float*)d_in[2];
  const float* w2s = (const float*)d_in[3];
  const float* w3s = (const float*)d_in[4];
  float* out = (float*)d_out;

  char* ws = (char*)d_ws;
  f16* xh = (f16*)ws;                                   // 8 MiB
  f16* inter = (f16*)(ws + ((size_t)8 << 20));          // 72 MiB (9216 rows)
  f16* w13t = (f16*)(ws + ((size_t)80 << 20));          // 128 MiB (interleaved w1|w3)
  f16* w2t = (f16*)(ws + ((size_t)208 << 20));          // 64 MiB
  char* meta = ws + ((size_t)272 << 20);
  int* counts = (int*)meta;
  int* bases = (int*)(meta + 512);
  int* lists = (int*)(meta + 1024);
  float* wgts = (float*)(meta + 1024 + (size_t)NE * T_TOK * 4);

  hipMemsetAsync(out, 0, (size_t)out_size * sizeof(float), stream);
  hipMemsetAsync(meta, 0, 1024 + (size_t)NE * T_TOK * 8, stream);

  cast_x_kernel<<<dim3((T_TOK * H_DIM) / (4 * 256)), dim3(256), 0, stream>>>(x, xh);
  router_kernel<<<dim3(T_TOK), dim3(64), 0, stream>>>(x, gw, counts, lists, wgts);
  prefix_kernel<<<dim3(1), dim3(64), 0, stream>>>(counts, bases);
  transpose_cast_kernel<<<dim3(64, 16, 24), dim3(256), 0, stream>>>(
      w1s, w3s, w2s, w13t, w2t);
  gemm_a_kernel<<<dim3((2 * I_DIM) / 256, T_TOK / 256, NE), dim3(512), 0, stream>>>(
      xh, w13t, counts, bases, lists, inter);
  gemm_b_kernel<<<dim3(H_DIM / 128, 2 * (T_TOK / 128), NE), dim3(256), 0, stream>>>(
      inter, w2t, counts, bases, lists, wgts, out);
}